// Round 13
// baseline (832.852 us; speedup 1.0000x reference)
//
#include <hip/hip_runtime.h>
#include <math.h>

// GaussianMixtureLayer: EM loop (<=8 iters, device-side convergence flag) +
// final update + Gaussian log-prob loss. Heavy GEMMs on bf16 MFMA (hi/lo
// 3-term split), operands in FRAGMENT ORDER (wave-contiguous dwordx4 loads).
//   k_quad   : Y = X Linv^T, w = ||y - t||^2; also zeroes CS for the scatter
//   k_scatter: S_k = (w.X)^T X + fused num/sw; B-load hoist + (256,2) VGPR
//              cap fix (r22: 54 -> ~25us).
//   k_fused  : update + Cholesky + two-level trinv; C and L never leave LDS.
//              Round-24 (= r23 resubmit; r23 bench died on container infra):
//              STRIP ELIMINATION — FACTOR self-corrects its 16 target columns
//              in registers (panel-P row values via 4 extra float4 loads;
//              column values via v_readlane from lane jj, which holds row
//              C0+jj). Deletes 7 strip passes + 7 of 14 phase-B barriers;
//              correction uses the strip's exact 4-product dot grouping.
//              Look-ahead retained: FACTOR(C0)+corr on waves 0-1 overlaps
//              rest-update(P) on waves 2-7 (write sets disjoint).

#define NS 16384
#define DD 128
#define KC 16
#define JITTER_ 1e-6f
#define EPS2_ 1e-6f            // (1e-3)^2 Frobenius convergence check
#define LOG_2PI_ 1.8378770664093454f
#define NCHUNK 1024            // scatter samples per chunk — 16 chunks

typedef __attribute__((ext_vector_type(8))) short bf16x8;
typedef __attribute__((ext_vector_type(16))) float f32x16;

// workspace float offsets
enum : int {
  OFF_CUR_M  = 0,            // 16*128
  OFF_CS     = 2048,         // 16*128*128  S accumulator (zeroed by k_quad)
  OFF_T      = 528384,       // t_k = Linv_k m_k (fp32)
  OFF_LOGDET = 530432,
  OFF_SW     = 530448,
  OFF_NUM    = 530464,       // 16*128
  OFF_W      = 532512,       // w[k][n]
  OFF_LOSSK  = 794656,       // 16 per-k loss partials
  OFF_DIFFSQ = 794672,
  OFF_DONE   = 794673,       // int
  OFF_CTR    = 794674,       // int, monotonic (no in-kernel reset)
  // frag-order bf16 arrays (ushort), 2 floats per 4 ushorts:
  OFF_XAH    = 794676,       // X row-side frags: [ng(512)][ec(4)][ks(2)][l(64)][8]
  OFF_XAL    = 1843252,
  OFF_XBH    = 2891828,      // X^T frags: [eg(4)][nb(1024)][l(64)][8]
  OFF_XBL    = 3940404,
  OFF_LBH    = 4988980,      // Linv frags per k: [k][dg(4)][ec(4)][ks(2)][l(64)][8]
  OFF_LBL    = 5120052,
  WS_FLOATS  = 5251124       // ~21 MB
};

__device__ __forceinline__ float bf2f(ushort u) {
  union { unsigned u; float f; } c; c.u = ((unsigned)u) << 16; return c.f;
}
__device__ __forceinline__ ushort f2bf_rne(float f) {
  union { float f; unsigned u; } c; c.f = f;
  unsigned r = c.u + 0x7fffu + ((c.u >> 16) & 1u);
  return (ushort)(r >> 16);
}
__device__ __forceinline__ ushort f2bf_trunc(float f) {
  union { float f; unsigned u; } c; c.f = f; return (ushort)(c.u >> 16);
}

// XOR-quad swizzle for 128x128 LDS matrix.
__device__ __forceinline__ int swz(int r, int c) {
  return (r << 7) + ((((c >> 2) + r) & 31) << 2) + (c & 3);
}

// broadcast from a compile-time-constant lane (v_readlane, not ds_bpermute)
__device__ __forceinline__ float rdlane(float v, int lane) {
  union { float f; int i; } c; c.f = v;
  c.i = __builtin_amdgcn_readlane(c.i, lane);
  return c.f;
}

// bf16 hi/lo split of one 8-float Linv fragment -> global frag arrays
__device__ __forceinline__ void frag_write(const float* Zs, ushort* LBH,
                                           ushort* LBL, int g) {
  int ll = g & 63, ks2 = (g >> 6) & 1, ec = (g >> 7) & 3, dg = (g >> 9) & 3;
  int d = 32 * dg + (ll & 31);
  int e = 32 * ec + 16 * ks2 + 8 * (ll >> 5);
  float4 z0 = *(const float4*)&Zs[d * 132 + e];
  float4 z1 = *(const float4*)&Zs[d * 132 + e + 4];
  float zv[8] = {z0.x, z0.y, z0.z, z0.w, z1.x, z1.y, z1.z, z1.w};
  ushort hh[8], lo2[8];
  #pragma unroll
  for (int j = 0; j < 8; ++j) {
    hh[j]  = f2bf_trunc(zv[j]);
    lo2[j] = f2bf_rne(zv[j] - bf2f(hh[j]));
  }
  *(ushort4*)&LBH[g * 8]     = make_ushort4(hh[0], hh[1], hh[2], hh[3]);
  *(ushort4*)&LBH[g * 8 + 4] = make_ushort4(hh[4], hh[5], hh[6], hh[7]);
  *(ushort4*)&LBL[g * 8]     = make_ushort4(lo2[0], lo2[1], lo2[2], lo2[3]);
  *(ushort4*)&LBL[g * 8 + 4] = make_ushort4(lo2[4], lo2[5], lo2[6], lo2[7]);
}

// init state + one-time bf16 hi/lo split of X into frag-order XA (row side)
// and XB (transposed side). Block b handles samples 64b..64b+63.
__global__ __launch_bounds__(256) void k_init_split(const float* __restrict__ x,
                                                    const float* __restrict__ means,
                                                    const float* __restrict__ covs,
                                                    float* __restrict__ ws) {
  __shared__ float xt[64 * 132];
  int b = blockIdx.x, t = threadIdx.x;
  int idx = b * 256 + t;
  for (int i = idx; i < KC * DD * DD; i += 256 * 256) ws[OFF_CS + i] = covs[i];
  if (idx < KC * DD) ws[OFF_CUR_M + idx] = means[idx];
  if (idx == 0) {
    ws[OFF_DIFFSQ] = 0.f;
    ((int*)ws)[OFF_DONE] = 0;
    ((int*)ws)[OFF_CTR]  = 0;
  }
  int n0 = b * 64;
  for (int fi = t; fi < 2048; fi += 256) {
    int n = fi >> 5, q = (fi & 31) * 4;
    *(float4*)&xt[n * 132 + q] = *(const float4*)&x[(size_t)(n0 + n) * DD + q];
  }
  __syncthreads();
  ushort* __restrict__ XAH = (ushort*)(ws + OFF_XAH);
  ushort* __restrict__ XAL = (ushort*)(ws + OFF_XAL);
  ushort* __restrict__ XBH = (ushort*)(ws + OFF_XBH);
  ushort* __restrict__ XBL = (ushort*)(ws + OFF_XBL);
  // XA: n = 32*ng+(l&31), e = 32ec+16ks+8(l>>5)+j
  for (int s = t; s < 1024; s += 256) {
    int l = s & 63, ks = (s >> 6) & 1, ec = (s >> 7) & 3, ngl = (s >> 9) & 1;
    int nl = 32 * ngl + (l & 31);
    int e0 = 32 * ec + 16 * ks + 8 * (l >> 5);
    float vv[8];
    *(float4*)&vv[0] = *(const float4*)&xt[nl * 132 + e0];
    *(float4*)&vv[4] = *(const float4*)&xt[nl * 132 + e0 + 4];
    ushort h[8], lo[8];
    #pragma unroll
    for (int j = 0; j < 8; ++j) {
      h[j]  = f2bf_trunc(vv[j]);
      lo[j] = f2bf_rne(vv[j] - bf2f(h[j]));
    }
    size_t base = ((((size_t)((n0 >> 5) + ngl) * 4 + ec) * 2 + ks) * 64 + l) * 8;
    *(ushort4*)&XAH[base]     = make_ushort4(h[0], h[1], h[2], h[3]);
    *(ushort4*)&XAH[base + 4] = make_ushort4(h[4], h[5], h[6], h[7]);
    *(ushort4*)&XAL[base]     = make_ushort4(lo[0], lo[1], lo[2], lo[3]);
    *(ushort4*)&XAL[base + 4] = make_ushort4(lo[4], lo[5], lo[6], lo[7]);
  }
  // XB: e = 32eg+(l&31), n = 16*nb+8(l>>5)+j
  for (int s = t; s < 1024; s += 256) {
    int l = s & 63, nbl = (s >> 6) & 3, eg = (s >> 8) & 3;
    int e = 32 * eg + (l & 31);
    int nl = 16 * nbl + 8 * (l >> 5);
    ushort h[8], lo[8];
    #pragma unroll
    for (int j = 0; j < 8; ++j) {
      float v = xt[(nl + j) * 132 + e];
      h[j]  = f2bf_trunc(v);
      lo[j] = f2bf_rne(v - bf2f(h[j]));
    }
    size_t base = (((size_t)eg * (NS / 16) + (n0 >> 4) + nbl) * 64 + l) * 8;
    *(ushort4*)&XBH[base]     = make_ushort4(h[0], h[1], h[2], h[3]);
    *(ushort4*)&XBH[base + 4] = make_ushort4(h[4], h[5], h[6], h[7]);
    *(ushort4*)&XBL[base]     = make_ushort4(lo[0], lo[1], lo[2], lo[3]);
    *(ushort4*)&XBL[base + 4] = make_ushort4(lo[4], lo[5], lo[6], lo[7]);
  }
}

// Fused update + Cholesky + triangular inverse. One block per component.
// 512 threads = 8 waves (2/SIMD -> 256-VGPR budget). Look-ahead schedule
// with strip-free self-correcting FACTOR (1 barrier per panel).
__global__ __launch_bounds__(512) void k_fused(float* __restrict__ ws, float* __restrict__ dout,
                                               int guarded, int do_update, int write_out,
                                               int accum_diff, int final_pass) {
  if (guarded && ((const int*)ws)[OFF_DONE]) return;
  __shared__ float m[DD * DD];      // 64 KB, swizzled: C then L
  __shared__ float Zs[DD * 132];    // 66 KB: Linv row-major
  __shared__ float Ws[64 * 68];     // 17 KB: GEMM temp
  __shared__ float invd_s[DD];
  __shared__ float cm_s[DD], nm_s[DD];
  __shared__ float redbuf[2];
  int k = blockIdx.x, t = threadIdx.x;
  int l = t & 63, wv = t >> 6;
  float* __restrict__ CS = ws + OFF_CS + (size_t)k * DD * DD;

  // ---------- phase A: build C in LDS (batched float4 loads, then sweep) ----
  if (do_update) {
    float sw = ws[OFF_SW + k];
    float inv = 1.f / sw;
    float4 s4v[8];
    #pragma unroll
    for (int it = 0; it < 8; ++it)
      s4v[it] = *(const float4*)&CS[(it * 512 + t) * 4];
    if (t < DD) {
      cm_s[t] = ws[OFF_CUR_M + k * DD + t];
      nm_s[t] = ws[OFF_NUM + k * DD + t];
    }
    __syncthreads();
    float* __restrict__ doutC = dout + 1 + KC * DD + (size_t)k * DD * DD;
    #pragma unroll
    for (int it = 0; it < 8; ++it) {
      int idx = (it * 512 + t) * 4;
      float4 s4 = s4v[it];
      int d = idx >> 7, e = idx & 127;
      float md = cm_s[d], nd = nm_s[d];
      float4 me4 = *(const float4*)&cm_s[e];
      float4 ne4 = *(const float4*)&nm_s[e];
      float4 v;
      v.x = (s4.x - md * ne4.x - nd * me4.x + sw * md * me4.x) * inv;
      v.y = (s4.y - md * ne4.y - nd * me4.y + sw * md * me4.y) * inv;
      v.z = (s4.z - md * ne4.z - nd * me4.z + sw * md * me4.z) * inv;
      v.w = (s4.w - md * ne4.w - nd * me4.w + sw * md * me4.w) * inv;
      if (d >= e && d < e + 4) (&v.x)[d - e] += JITTER_;
      *(float4*)&m[swz(d, e)] = v;
      if (write_out) *(float4*)&doutC[idx] = v;
    }
    if (t < DD) {
      float me = cm_s[t], ne = nm_s[t];
      float newm = ne * inv;
      ws[OFF_CUR_M + k * DD + t] = newm;
      if (write_out) dout[1 + k * DD + t] = newm;
      if (accum_diff) {
        float dm = newm - me;
        float s = dm * dm;
        #pragma unroll
        for (int mk2 = 1; mk2 < 64; mk2 <<= 1) s += __shfl_xor(s, mk2, 64);
        if (l == 0) redbuf[wv] = s;
      }
      ws[OFF_NUM + k * DD + t] = 0.f;
    }
    if (t == 0) {
      ws[OFF_SW + k] = 0.f;
      if (final_pass) ws[OFF_LOSSK + k] = 0.f;
    }
  } else {
    #pragma unroll
    for (int it = 0; it < 8; ++it) {
      int idx = (it * 512 + t) * 4;
      float4 c4 = *(const float4*)&CS[idx];
      *(float4*)&m[swz(idx >> 7, idx & 127)] = c4;
    }
    if (t < DD) ws[OFF_NUM + k * DD + t] = 0.f;
    if (t == 0) ws[OFF_SW + k] = 0.f;
  }
  __syncthreads();

  // ---------- phase B: strip-free look-ahead Cholesky, PANEL=16 ----------
  // FACTOR(C0, P0, corr): waves 0-1 load the 16 target columns, self-correct
  // with panel P0 in registers (col panel values broadcast via v_readlane
  // from lane jj, which holds row C0+jj), then run the factor chain.
  auto FACTOR = [&](int P, int P0, bool corr) {
    int ra = P + l, rb = P + 64 + l;
    bool isA = (wv == 0);
    bool va = ra < DD, vb = rb < DD;
    float A[16], B[16];
    if (va) {
      #pragma unroll
      for (int q = 0; q < 4; ++q) {
        float4 v = *(const float4*)&m[swz(ra, P + 4 * q)];
        A[4*q+0] = v.x; A[4*q+1] = v.y; A[4*q+2] = v.z; A[4*q+3] = v.w;
      }
    }
    if (!isA && vb) {
      #pragma unroll
      for (int q = 0; q < 4; ++q) {
        float4 v = *(const float4*)&m[swz(rb, P + 4 * q)];
        B[4*q+0] = v.x; B[4*q+1] = v.y; B[4*q+2] = v.z; B[4*q+3] = v.w;
      }
    }
    if (corr) {
      if (isA) {
        // row panel values (rows P+l); col P+jj's panel = lane jj's rp
        float4 rp[4];
        if (va) {
          #pragma unroll
          for (int q = 0; q < 4; ++q) rp[q] = *(const float4*)&m[swz(ra, P0 + 4 * q)];
        }
        #pragma unroll
        for (int jj = 0; jj < 16; ++jj) {
          float acc = 0.f;
          #pragma unroll
          for (int pq = 0; pq < 4; ++pq) {
            float bx = rdlane(rp[pq].x, jj), by = rdlane(rp[pq].y, jj);
            float bz = rdlane(rp[pq].z, jj), bw = rdlane(rp[pq].w, jj);
            acc += rp[pq].x * bx + rp[pq].y * by + rp[pq].z * bz + rp[pq].w * bw;
          }
          if (va) A[jj] -= acc;
        }
      } else {
        // B rows: row panel values + broadcast copy of rows P+l for cols
        float4 bp[4], cp[4];
        int rc = P + l; if (rc > DD - 1) rc = DD - 1;   // clamp (lanes>=16 unused)
        #pragma unroll
        for (int q = 0; q < 4; ++q) cp[q] = *(const float4*)&m[swz(rc, P0 + 4 * q)];
        if (vb) {
          #pragma unroll
          for (int q = 0; q < 4; ++q) bp[q] = *(const float4*)&m[swz(rb, P0 + 4 * q)];
        }
        #pragma unroll
        for (int jj = 0; jj < 16; ++jj) {
          float acc = 0.f;
          #pragma unroll
          for (int pq = 0; pq < 4; ++pq) {
            float bx = rdlane(cp[pq].x, jj), by = rdlane(cp[pq].y, jj);
            float bz = rdlane(cp[pq].z, jj), bw = rdlane(cp[pq].w, jj);
            acc += bp[pq].x * bx + bp[pq].y * by + bp[pq].z * bz + bp[pq].w * bw;
          }
          if (vb) B[jj] -= acc;
        }
      }
    }
    #pragma unroll
    for (int jj = 0; jj < 16; ++jj) {
      float dj = rdlane(A[jj], jj);
      float inv = __builtin_amdgcn_rsqf(dj);
      inv = inv * (1.5f - 0.5f * dj * inv * inv);   // 1 Newton -> ~fp32 exact
      float sj = dj * inv;
      if (va) {
        if (l == jj) A[jj] = sj;
        else if (l > jj) A[jj] *= inv;
      }
      if (!isA && vb) B[jj] *= inv;
      #pragma unroll
      for (int jj2 = jj + 1; jj2 < 16; ++jj2) {
        float c = rdlane(A[jj], jj2);
        if (va && l > jj) A[jj2] -= A[jj] * c;
        if (!isA && vb) B[jj2] -= B[jj] * c;
      }
    }
    if (isA && va) {
      #pragma unroll
      for (int q = 0; q < 4; ++q)
        *(float4*)&m[swz(ra, P + 4 * q)] = make_float4(A[4*q], A[4*q+1], A[4*q+2], A[4*q+3]);
    }
    if (!isA && vb) {
      #pragma unroll
      for (int q = 0; q < 4; ++q)
        *(float4*)&m[swz(rb, P + 4 * q)] = make_float4(B[4*q], B[4*q+1], B[4*q+2], B[4*q+3]);
    }
  };
  // rank-16 8x8 tile update (rest): m[i0..+7][q0..+7] -= panel partial
  auto TILE8 = [&](int i0, int q0, int P) {
    float acc8[8][8] = {};
    #pragma unroll
    for (int pq = 0; pq < 4; ++pq) {
      float4 a[8], b[8];
      #pragma unroll
      for (int r = 0; r < 8; ++r) a[r] = *(const float4*)&m[swz(i0 + r, P + 4 * pq)];
      #pragma unroll
      for (int c = 0; c < 8; ++c) b[c] = *(const float4*)&m[swz(q0 + c, P + 4 * pq)];
      #pragma unroll
      for (int r = 0; r < 8; ++r)
        #pragma unroll
        for (int c = 0; c < 8; ++c)
          acc8[r][c] += a[r].x * b[c].x + a[r].y * b[c].y +
                        a[r].z * b[c].z + a[r].w * b[c].w;
    }
    #pragma unroll
    for (int r = 0; r < 8; ++r)
      #pragma unroll
      for (int cq = 0; cq < 2; ++cq) {
        float4 v = *(const float4*)&m[swz(i0 + r, q0 + 4 * cq)];
        v.x -= acc8[r][4*cq+0]; v.y -= acc8[r][4*cq+1];
        v.z -= acc8[r][4*cq+2]; v.w -= acc8[r][4*cq+3];
        *(float4*)&m[swz(i0 + r, q0 + 4 * cq)] = v;
      }
  };

  if (wv < 2) FACTOR(0, 0, false);
  __syncthreads();
  for (int P = 0; P < DD - 16; P += 16) {
    int C0 = P + 16;
    if (wv < 2) {
      FACTOR(C0, P, true);                  // self-corrects with panel P
    } else {
      int R0 = P + 32, s = DD - R0;
      if (s > 0) {
        int nt = s >> 3, tri = (nt * (nt + 1)) >> 1;   // 8x8 tiles, <=78
        for (int idx = t - 128; idx < tri; idx += 384) {
          int ti = (int)(0.5f * (sqrtf(8.f * (float)idx + 1.f) - 1.f));
          while (((ti + 1) * (ti + 2)) >> 1 <= idx) ++ti;
          while ((ti * (ti + 1)) >> 1 > idx) --ti;
          int tj = idx - ((ti * (ti + 1)) >> 1);
          TILE8(R0 + 8 * ti, R0 + 8 * tj, P);
        }
      }
    }
    __syncthreads();
  }

  // ---------- phase C: trinv via 32x32 diag blocks + combine GEMMs ----------
  if (t < DD) {
    float dv = m[swz(t, t)];
    invd_s[t] = 1.f / dv;
    if (final_pass) {
      float lg = logf(dv);
      #pragma unroll
      for (int mk2 = 1; mk2 < 64; mk2 <<= 1) lg += __shfl_xor(lg, mk2, 64);
      if (l == 0) redbuf[wv] = lg;
    }
  }
  __syncthreads();
  if (wv < 4) {
    // invert 4 diagonal 32x32 lower-tri blocks; wave wv owns block wv.
    int j = l & 31, r0 = 32 * wv, row = r0 + (l & 31);
    float M[32];
    #pragma unroll
    for (int q = 0; q < 8; ++q) {
      float4 v = *(const float4*)&m[swz(row, r0 + 4 * q)];
      M[4*q+0] = v.x; M[4*q+1] = v.y; M[4*q+2] = v.z; M[4*q+3] = v.w;
    }
    float acc[32];
    #pragma unroll
    for (int i2 = 0; i2 < 32; ++i2) acc[i2] = 0.f;
    #pragma unroll
    for (int p = 0; p < 32; ++p) {
      float zp = (((p == j) ? 1.f : 0.f) - acc[p]) * invd_s[r0 + p];
      Zs[(r0 + p) * 132 + r0 + j] = zp;   // lanes l and l+32: same addr/value
      #pragma unroll
      for (int i2 = p + 1; i2 < 32; ++i2)
        acc[i2] += rdlane(M[p], i2) * zp;
    }
  } else {
    // zero the never-written Zs regions:
    //  a) rows 0..63, cols 64..127   (1024 float4)
    //  b) rows h64..h64+31, cols h64+32..h64+63, h=0,1  (2*256 float4)
    for (int z = t - 256; z < 1536; z += 256) {
      int r, c;
      if (z < 1024) { r = z >> 4; c = 64 + ((z & 15) << 2); }
      else { int z2 = z - 1024; int h = z2 >> 8; int z3 = z2 & 255;
             r = h * 64 + (z3 >> 3); c = h * 64 + 32 + ((z3 & 7) << 2); }
      *(float4*)&Zs[r * 132 + c] = make_float4(0.f, 0.f, 0.f, 0.f);
    }
    if (final_pass && t == 256) ws[OFF_LOGDET + k] = 2.f * (redbuf[0] + redbuf[1]);
  }
  __syncthreads();
  // 32-level combine stage 1: T = L21 * invD(2h)  -> Ws[h*32+i][j]
  {
    int h = t >> 8, i = (t >> 3) & 31, j0 = (t & 7) << 2;
    int rI = h * 64 + 32 + i, cb = h * 64;
    float ax = 0.f, ay = 0.f, az = 0.f, aw = 0.f;
    #pragma unroll
    for (int q0 = 0; q0 < 32; q0 += 4) {
      float4 a  = *(const float4*)&m[swz(rI, cb + q0)];
      float4 z0 = *(const float4*)&Zs[(cb + q0 + 0) * 132 + cb + j0];
      float4 z1 = *(const float4*)&Zs[(cb + q0 + 1) * 132 + cb + j0];
      float4 z2 = *(const float4*)&Zs[(cb + q0 + 2) * 132 + cb + j0];
      float4 z3 = *(const float4*)&Zs[(cb + q0 + 3) * 132 + cb + j0];
      ax += a.x * z0.x + a.y * z1.x + a.z * z2.x + a.w * z3.x;
      ay += a.x * z0.y + a.y * z1.y + a.z * z2.y + a.w * z3.y;
      az += a.x * z0.z + a.y * z1.z + a.z * z2.z + a.w * z3.z;
      aw += a.x * z0.w + a.y * z1.w + a.z * z2.w + a.w * z3.w;
    }
    *(float4*)&Ws[(h * 32 + i) * 68 + j0] = make_float4(ax, ay, az, aw);
  }
  __syncthreads();
  // stage 2: Zs 32-offdiag = -invD(2h+1) * T
  {
    int h = t >> 8, i = (t >> 3) & 31, j0 = (t & 7) << 2;
    int rI = h * 64 + 32 + i;
    float ax = 0.f, ay = 0.f, az = 0.f, aw = 0.f;
    #pragma unroll
    for (int q0 = 0; q0 < 32; q0 += 4) {
      float4 a  = *(const float4*)&Zs[rI * 132 + h * 64 + 32 + q0];
      float4 w0 = *(const float4*)&Ws[(h * 32 + q0 + 0) * 68 + j0];
      float4 w1 = *(const float4*)&Ws[(h * 32 + q0 + 1) * 68 + j0];
      float4 w2 = *(const float4*)&Ws[(h * 32 + q0 + 2) * 68 + j0];
      float4 w3 = *(const float4*)&Ws[(h * 32 + q0 + 3) * 68 + j0];
      ax += a.x * w0.x + a.y * w1.x + a.z * w2.x + a.w * w3.x;
      ay += a.x * w0.y + a.y * w1.y + a.z * w2.y + a.w * w3.y;
      az += a.x * w0.z + a.y * w1.z + a.z * w2.z + a.w * w3.z;
      aw += a.x * w0.w + a.y * w1.w + a.z * w2.w + a.w * w3.w;
    }
    *(float4*)&Zs[rI * 132 + h * 64 + j0] = make_float4(-ax, -ay, -az, -aw);
  }
  __syncthreads();
  // 64-level combine GEMMs on 128 threads (8x4 register tiles) overlapped
  // with bf16 frag stores on threads 128..511.
  ushort* __restrict__ LBH = (ushort*)(ws + OFF_LBH) + (size_t)k * 16384;
  ushort* __restrict__ LBL = (ushort*)(ws + OFF_LBL) + (size_t)k * 16384;
  if (t < 128) {  // GEMM1: W = L21(64) * Ainv -> Ws
    int i0 = (t >> 4) << 3, j0 = (t & 15) << 2;
    float acc4[8][4] = {};
    for (int q0 = 0; q0 < 64; q0 += 4) {
      float4 a[8], b[4];
      #pragma unroll
      for (int r = 0; r < 8; ++r) a[r] = *(const float4*)&m[swz(64 + i0 + r, q0)];
      #pragma unroll
      for (int s2 = 0; s2 < 4; ++s2) b[s2] = *(const float4*)&Zs[(q0 + s2) * 132 + j0];
      #pragma unroll
      for (int r = 0; r < 8; ++r) {
        acc4[r][0] += a[r].x * b[0].x + a[r].y * b[1].x + a[r].z * b[2].x + a[r].w * b[3].x;
        acc4[r][1] += a[r].x * b[0].y + a[r].y * b[1].y + a[r].z * b[2].y + a[r].w * b[3].y;
        acc4[r][2] += a[r].x * b[0].z + a[r].y * b[1].z + a[r].z * b[2].z + a[r].w * b[3].z;
        acc4[r][3] += a[r].x * b[0].w + a[r].y * b[1].w + a[r].z * b[2].w + a[r].w * b[3].w;
      }
    }
    #pragma unroll
    for (int r = 0; r < 8; ++r)
      *(float4*)&Ws[(i0 + r) * 68 + j0] =
          make_float4(acc4[r][0], acc4[r][1], acc4[r][2], acc4[r][3]);
  } else {        // ready frags, part 1: g in [0,768) (all dg<2), 2 each
    #pragma unroll
    for (int it = 0; it < 2; ++it) frag_write(Zs, LBH, LBL, (t - 128) + it * 384);
  }
  __syncthreads();
  if (t < 128) {  // GEMM2: Zs[64+i][j] = -Binv * W
    int i0 = (t >> 4) << 3, j0 = (t & 15) << 2;
    float acc4[8][4] = {};
    for (int q0 = 0; q0 < 64; q0 += 4) {
      float4 a[8], b[4];
      #pragma unroll
      for (int r = 0; r < 8; ++r)
        a[r] = *(const float4*)&Zs[(64 + i0 + r) * 132 + 64 + q0];
      #pragma unroll
      for (int s2 = 0; s2 < 4; ++s2) b[s2] = *(const float4*)&Ws[(q0 + s2) * 68 + j0];
      #pragma unroll
      for (int r = 0; r < 8; ++r) {
        acc4[r][0] += a[r].x * b[0].x + a[r].y * b[1].x + a[r].z * b[2].x + a[r].w * b[3].x;
        acc4[r][1] += a[r].x * b[0].y + a[r].y * b[1].y + a[r].z * b[2].y + a[r].w * b[3].y;
        acc4[r][2] += a[r].x * b[0].z + a[r].y * b[1].z + a[r].z * b[2].z + a[r].w * b[3].z;
        acc4[r][3] += a[r].x * b[0].w + a[r].y * b[1].w + a[r].z * b[2].w + a[r].w * b[3].w;
      }
    }
    #pragma unroll
    for (int r = 0; r < 8; ++r)
      *(float4*)&Zs[(64 + i0 + r) * 132 + j0] =
          make_float4(-acc4[r][0], -acc4[r][1], -acc4[r][2], -acc4[r][3]);
  } else {        // ready frags, part 2: r in [768,1536), 2 each
    #pragma unroll
    for (int it = 0; it < 2; ++it) {
      int r = 768 + (t - 128) + it * 384;
      int g;
      if (r < 1024) g = r;
      else { int rr = r - 1024;
             g = (2 + (rr >> 8)) * 512 + (2 + ((rr >> 7) & 1)) * 128 + (rr & 127); }
      frag_write(Zs, LBH, LBL, g);
    }
  }
  __syncthreads();
  if (t < DD) {   // t = Linv * m  (NEW means)
    const float* __restrict__ mk = ws + OFF_CUR_M + k * DD;
    float s0 = 0.f;
    for (int e = 0; e < DD; e += 4) {
      float4 z = *(const float4*)&Zs[t * 132 + e];
      s0 += z.x * mk[e] + z.y * mk[e + 1] + z.z * mk[e + 2] + z.w * mk[e + 3];
    }
    ws[OFF_T + k * DD + t] = s0;
  } else {        // pending frags: (dg>=2, ec<2), 512 total
    for (int rr = t - 128; rr < 512; rr += 384) {
      int g = (2 + (rr >> 8)) * 512 + ((rr >> 7) & 1) * 128 + (rr & 127);
      frag_write(Zs, LBH, LBL, g);
    }
  }
  // convergence atomics at the very END (off the phase-B critical path);
  // redbuf survives from phase A (phase C writes it only under final_pass,
  // which is mutually exclusive with accum_diff).
  if (accum_diff && t == 0) {
    atomicAdd(&ws[OFF_DIFFSQ], redbuf[0] + redbuf[1]);
    __threadfence();
    int old = atomicAdd((int*)ws + OFF_CTR, 1);
    if ((old & (KC - 1)) == KC - 1) {
      float v = atomicAdd(&ws[OFF_DIFFSQ], 0.f);
      if (v <= EPS2_) atomicExch((int*)ws + OFF_DONE, 1);
      atomicExch(&ws[OFF_DIFFSQ], 0.f);
    }
  }
}

// w[n,k] = ||X Linv^T - t||^2. Block: 128 samples x full 128 d, 4 waves.
// Also zeroes this block's slice of CS for the upcoming k_scatter.
__global__ __launch_bounds__(256) void k_quad(float* __restrict__ ws,
                                              const float* __restrict__ wts,
                                              int guarded, int final_pass) {
  if (guarded && ((const int*)ws)[OFF_DONE]) return;
  __shared__ float warr[128];
  int k = blockIdx.y, bx = blockIdx.x, t = threadIdx.x;
  int l = t & 63, wv = t >> 6;
  int n0 = bx * 128;
  if (t < 128) ws[OFF_CS + (size_t)k * DD * DD + bx * 128 + t] = 0.f;
  const ushort* __restrict__ XAH = (const ushort*)(ws + OFF_XAH);
  const ushort* __restrict__ XAL = (const ushort*)(ws + OFF_XAL);
  const ushort* __restrict__ LBH = (const ushort*)(ws + OFF_LBH) + (size_t)k * 16384;
  const ushort* __restrict__ LBL = (const ushort*)(ws + OFF_LBL) + (size_t)k * 16384;
  f32x16 acc[4] = {};
  size_t ng4 = (size_t)(4 * bx + wv) * 4;
  #pragma unroll
  for (int ec = 0; ec < 4; ++ec) {
    #pragma unroll
    for (int ks = 0; ks < 2; ++ks) {
      size_t aoff = (((ng4 + ec) * 2 + ks) * 64 + l) * 8;
      bf16x8 ah = *(const bf16x8*)&XAH[aoff];
      bf16x8 al = *(const bf16x8*)&XAL[aoff];
      #pragma unroll
      for (int dg = 0; dg < 4; ++dg) {
        size_t boff = ((((size_t)dg * 4 + ec) * 2 + ks) * 64 + l) * 8;
        bf16x8 bh = *(const bf16x8*)&LBH[boff];
        bf16x8 bl = *(const bf16x8*)&LBL[boff];
        acc[dg] = __builtin_amdgcn_mfma_f32_32x32x16_bf16(ah, bh, acc[dg], 0, 0, 0);
        acc[dg] = __builtin_amdgcn_mfma_f32_32x32x16_bf16(ah, bl, acc[dg], 0, 0, 0);
        acc[dg] = __builtin_amdgcn_mfma_f32_32x32x16_bf16(al, bh, acc[dg], 0, 0, 0);
      }
    }
  }
  float tv[4];
  #pragma unroll
  for (int c = 0; c < 4; ++c) tv[c] = ws[OFF_T + k * DD + 32 * c + (l & 31)];
  float part[16];
  #pragma unroll
  for (int r = 0; r < 16; ++r) {
    float s = 0.f;
    #pragma unroll
    for (int c = 0; c < 4; ++c) { float d = acc[c][r] - tv[c]; s += d * d; }
    part[r] = s;
  }
  #pragma unroll
  for (int mk2 = 1; mk2 < 32; mk2 <<= 1)
    #pragma unroll
    for (int r = 0; r < 16; ++r) part[r] += __shfl_xor(part[r], mk2, 64);
  int h = l >> 5;
  if ((l & 31) < 16) {
    int r = l & 31;
    int row = (r & 3) + 8 * (r >> 2) + 4 * h + 32 * wv;   // verified C/D layout
    ws[OFF_W + k * NS + n0 + row] = part[r];
    if (final_pass) warr[row] = part[r];
  }
  if (final_pass) {
    __syncthreads();
    if (t < 64) {
      float s = warr[t] + warr[t + 64];
      #pragma unroll
      for (int mk2 = 1; mk2 < 64; mk2 <<= 1) s += __shfl_xor(s, mk2, 64);
      if (t == 0) atomicAdd(&ws[OFF_LOSSK + k], 0.5f * wts[k] * s);
    }
  }
}

// S_k += (w.X)^T X. 1D grid, XCD-locality decode; 16 chunks x 4 dg x 16 k =
// 1024 blocks, 32KB two-phase LDS reduce. B-frag loads hoisted to the top of
// each iteration (covered by the VALU re-split); __launch_bounds__(256, 2)
// keeps the hoisted frags in registers (r22: 54 -> ~25us).
__global__ __launch_bounds__(256, 2) void k_scatter(float* __restrict__ ws, int guarded) {
  if (guarded && ((const int*)ws)[OFF_DONE]) return;
  __shared__ float Sred[8192];     // 32 KB: [wv(4)][egL(2)][r(16)][l(64)]
  int id = blockIdx.x, t = threadIdx.x;
  int xcd = id & 7, j = id >> 3;
  int chunk = xcd + 8 * (j & 1);   // same-chunk blocks share an XCD's L2
  int dg = (j >> 1) & 3;
  int k = j >> 3;
  int l = t & 63, wv = t >> 6;     // wv = K-quarter within the chunk
  const ushort* __restrict__ XBH = (const ushort*)(ws + OFF_XBH);
  const ushort* __restrict__ XBL = (const ushort*)(ws + OFF_XBL);
  const float* __restrict__ wp = ws + OFF_W + k * NS + chunk * NCHUNK;
  f32x16 acc[4] = {};
  int nb0 = chunk * (NCHUNK / 16) + wv * (NCHUNK / 64);  // 16-sample groups
  int ko = (l >> 5) * 8;
  float zsum = 0.f, wsum = 0.f;
  // prologue: A-frag + w loads for st=0
  size_t aoff = (((size_t)dg * (NS / 16) + nb0) * 64 + l) * 8;
  bf16x8 th = *(const bf16x8*)&XBH[aoff];
  bf16x8 tl = *(const bf16x8*)&XBL[aoff];
  float4 w0 = *(const float4*)&wp[16 * (wv * (NCHUNK / 64)) + ko];
  float4 w1 = *(const float4*)&wp[16 * (wv * (NCHUNK / 64)) + ko + 4];
  for (int st = 0; st < NCHUNK / 64; ++st) {             // 16 iters
    // (1) issue ALL current-st B-frag loads first (8 VMEM in flight)
    bf16x8 bh[4], bl[4];
    #pragma unroll
    for (int eg = 0; eg < 4; ++eg) {
      size_t boff = (((size_t)eg * (NS / 16) + nb0 + st) * 64 + l) * 8;
      bh[eg] = *(const bf16x8*)&XBH[boff];
      bl[eg] = *(const bf16x8*)&XBL[boff];
    }
    // (2) prefetch next-iter A-frags + w (mod-16 clamp, no branch)
    int stn = (st + 1) & (NCHUNK / 64 - 1);
    size_t aoffn = (((size_t)dg * (NS / 16) + nb0 + stn) * 64 + l) * 8;
    bf16x8 thn = *(const bf16x8*)&XBH[aoffn];
    bf16x8 tln = *(const bf16x8*)&XBL[aoffn];
    int wbn = 16 * (wv * (NCHUNK / 64) + stn) + ko;
    float4 w0n = *(const float4*)&wp[wbn];
    float4 w1n = *(const float4*)&wp[wbn + 4];
    // (3) VALU re-split of the A operand — covers the in-flight loads
    float wj[8] = {w0.x, w0.y, w0.z, w0.w, w1.x, w1.y, w1.z, w1.w};
    bf16x8 ah, al;
    #pragma unroll
    for (int jj = 0; jj < 8; ++jj) {
      float xf = bf2f((ushort)th[jj]) + bf2f((ushort)tl[jj]);
      float zf = wj[jj] * xf;
      zsum += zf;                              // num[d] partial
      union { float f; unsigned u; } cz; cz.f = zf;
      ah[jj] = (short)(ushort)(cz.u >> 16);
      union { unsigned u; float f; } ch; ch.u = cz.u & 0xffff0000u;
      al[jj] = (short)f2bf_rne(zf - ch.f);
    }
    if (dg == 0 && (l & 31) == 0) {            // sw partial: 2 lanes/wave
      #pragma unroll
      for (int jj = 0; jj < 8; ++jj) wsum += wj[jj];
    }
    // (4) MFMA block — operands already resident
    #pragma unroll
    for (int eg = 0; eg < 4; ++eg) {
      acc[eg] = __builtin_amdgcn_mfma_f32_32x32x16_bf16(ah, bh[eg], acc[eg], 0, 0, 0);
      acc[eg] = __builtin_amdgcn_mfma_f32_32x32x16_bf16(ah, bl[eg], acc[eg], 0, 0, 0);
      acc[eg] = __builtin_amdgcn_mfma_f32_32x32x16_bf16(al, bh[eg], acc[eg], 0, 0, 0);
    }
    th = thn; tl = tln; w0 = w0n; w1 = w1n;
  }
  // num epilogue: each wave covers a disjoint K-quarter; lanes l and l^32
  // share the same d -> combine then add (d = 32*dg + l).
  zsum += __shfl_xor(zsum, 32, 64);
  if (l < 32) atomicAdd(&ws[OFF_NUM + k * DD + 32 * dg + l], zsum);
  if (dg == 0) {
    wsum += __shfl_xor(wsum, 32, 64);
    if (l == 0) atomicAdd(&ws[OFF_SW + k], wsum);
  }
  // S epilogue: two-phase LDS reduce across the 4 K-quarter waves (32 KB),
  // one atomicAdd per element per block.
  float* __restrict__ S = ws + OFF_CS + (size_t)k * DD * DD;
  #pragma unroll
  for (int p = 0; p < 2; ++p) {
    if (p) __syncthreads();                   // protect Sred reuse
    #pragma unroll
    for (int egL = 0; egL < 2; ++egL)
      #pragma unroll
      for (int r = 0; r < 16; ++r)
        Sred[(wv * 2 + egL) * 1024 + r * 64 + l] = acc[2 * p + egL][r];
    __syncthreads();
    #pragma unroll
    for (int i = 0; i < 8; ++i) {
      int idx = i * 256 + t;
      int ll = idx & 63, r = (idx >> 6) & 15, egL = idx >> 10;
      int base = egL * 1024 + r * 64 + ll;
      float s = Sred[base] + Sred[base + 2048] + Sred[base + 4096] + Sred[base + 6144];
      int h = ll >> 5;
      int drow = 32 * dg + (r & 3) + 8 * (r >> 2) + 4 * h;
      int e = 32 * (2 * p + egL) + (ll & 31);
      atomicAdd(&S[drow * DD + e], s);
    }
  }
}

__global__ void k_lossfin(const float* __restrict__ weights, const float* __restrict__ ws,
                          float* __restrict__ dout) {
  if (threadIdx.x == 0 && blockIdx.x == 0) {
    float base = 0.f;
    for (int k = 0; k < KC; ++k)
      base += weights[k] * 0.5f * (float)NS * ((float)DD * LOG_2PI_ + ws[OFF_LOGDET + k])
            + ws[OFF_LOSSK + k];
    dout[0] = base;
  }
}

extern "C" void kernel_launch(void* const* d_in, const int* in_sizes, int n_in,
                              void* d_out, int out_size, void* d_ws, size_t ws_size,
                              hipStream_t stream) {
  const float* x       = (const float*)d_in[0];
  const float* means   = (const float*)d_in[1];
  const float* covs    = (const float*)d_in[2];
  const float* weights = (const float*)d_in[3];
  float* out = (float*)d_out;
  float* ws  = (float*)d_ws;

  hipLaunchKernelGGL(k_init_split, dim3(NS / 64), dim3(256), 0, stream, x, means, covs, ws);
  // first factorization of the initial covariances (no update phase)
  hipLaunchKernelGGL(k_fused, dim3(16), dim3(512), 0, stream, ws, out, 0, 0, 0, 0, 0);

  // 8 guarded EM iterations: w accumulation, then fused update+chol+trinv
  for (int u = 0; u < 8; ++u) {
    hipLaunchKernelGGL(k_quad,    dim3(128, 16), dim3(256), 0, stream, ws, weights, 1, 0);
    hipLaunchKernelGGL(k_scatter, dim3(1024), dim3(256), 0, stream, ws, 1);
    hipLaunchKernelGGL(k_fused,   dim3(16), dim3(512), 0, stream, ws, out, 1, 1, 0, 1, 0);
  }

  // final (always-executed) update + chol/trinv of c_fin, then loss
  hipLaunchKernelGGL(k_quad,    dim3(128, 16), dim3(256), 0, stream, ws, weights, 0, 0);
  hipLaunchKernelGGL(k_scatter, dim3(1024), dim3(256), 0, stream, ws, 0);
  hipLaunchKernelGGL(k_fused,   dim3(16), dim3(512), 0, stream, ws, out, 0, 1, 1, 0, 1);
  hipLaunchKernelGGL(k_quad,    dim3(128, 16), dim3(256), 0, stream, ws, weights, 0, 1);
  hipLaunchKernelGGL(k_lossfin, dim3(1), dim3(64), 0, stream, weights, ws, out);
}

// Round 14
// 804.889 us; speedup vs baseline: 1.0347x; 1.0347x over previous
//
#include <hip/hip_runtime.h>
#include <math.h>

// GaussianMixtureLayer: EM loop (<=8 iters, device-side convergence flag) +
// final update + Gaussian log-prob loss. Heavy GEMMs on bf16 MFMA (hi/lo
// 3-term split), operands in FRAGMENT ORDER (wave-contiguous dwordx4 loads).
//   k_quad   : Y = X Linv^T, w = ||y - t||^2; also zeroes CS for the scatter
//   k_scatter: S_k = (w.X)^T X + fused num/sw; B-load hoist + (256,2) VGPR
//              cap fix (r22: 54 -> ~25us).
//   k_fused  : update + Cholesky + two-level trinv; C and L never leave LDS.
//              Round-25: REVERT to the round-11 state (819us session best).
//              r23/r24's strip elimination regressed (53.5 -> 60.2us): the
//              strip ran data-parallel on 512 threads, but the in-register
//              self-correction it replaced ran SERIALLY on the critical
//              FACTOR waves (~400 instr/panel ahead of the factor chain) —
//              barrier savings (~1.4k cy) < added critical-path work (~3k).
//              k_fused is pinned by the serial panel-factor chain at 2
//              waves/SIMD: more waves dead (64-VGPR cap r16-18), LDS-issue
//              cuts neutral (r20), barrier cuts regress (r23). This state =
//              look-ahead + 2-wave FACTOR + 8x8 rest tiles + strip.

#define NS 16384
#define DD 128
#define KC 16
#define JITTER_ 1e-6f
#define EPS2_ 1e-6f            // (1e-3)^2 Frobenius convergence check
#define LOG_2PI_ 1.8378770664093454f
#define NCHUNK 1024            // scatter samples per chunk — 16 chunks

typedef __attribute__((ext_vector_type(8))) short bf16x8;
typedef __attribute__((ext_vector_type(16))) float f32x16;

// workspace float offsets
enum : int {
  OFF_CUR_M  = 0,            // 16*128
  OFF_CS     = 2048,         // 16*128*128  S accumulator (zeroed by k_quad)
  OFF_T      = 528384,       // t_k = Linv_k m_k (fp32)
  OFF_LOGDET = 530432,
  OFF_SW     = 530448,
  OFF_NUM    = 530464,       // 16*128
  OFF_W      = 532512,       // w[k][n]
  OFF_LOSSK  = 794656,       // 16 per-k loss partials
  OFF_DIFFSQ = 794672,
  OFF_DONE   = 794673,       // int
  OFF_CTR    = 794674,       // int, monotonic (no in-kernel reset)
  // frag-order bf16 arrays (ushort), 2 floats per 4 ushorts:
  OFF_XAH    = 794676,       // X row-side frags: [ng(512)][ec(4)][ks(2)][l(64)][8]
  OFF_XAL    = 1843252,
  OFF_XBH    = 2891828,      // X^T frags: [eg(4)][nb(1024)][l(64)][8]
  OFF_XBL    = 3940404,
  OFF_LBH    = 4988980,      // Linv frags per k: [k][dg(4)][ec(4)][ks(2)][l(64)][8]
  OFF_LBL    = 5120052,
  WS_FLOATS  = 5251124       // ~21 MB
};

__device__ __forceinline__ float bf2f(ushort u) {
  union { unsigned u; float f; } c; c.u = ((unsigned)u) << 16; return c.f;
}
__device__ __forceinline__ ushort f2bf_rne(float f) {
  union { float f; unsigned u; } c; c.f = f;
  unsigned r = c.u + 0x7fffu + ((c.u >> 16) & 1u);
  return (ushort)(r >> 16);
}
__device__ __forceinline__ ushort f2bf_trunc(float f) {
  union { float f; unsigned u; } c; c.f = f; return (ushort)(c.u >> 16);
}

// XOR-quad swizzle for 128x128 LDS matrix.
__device__ __forceinline__ int swz(int r, int c) {
  return (r << 7) + ((((c >> 2) + r) & 31) << 2) + (c & 3);
}

// broadcast from a compile-time-constant lane (v_readlane, not ds_bpermute)
__device__ __forceinline__ float rdlane(float v, int lane) {
  union { float f; int i; } c; c.f = v;
  c.i = __builtin_amdgcn_readlane(c.i, lane);
  return c.f;
}

// bf16 hi/lo split of one 8-float Linv fragment -> global frag arrays
__device__ __forceinline__ void frag_write(const float* Zs, ushort* LBH,
                                           ushort* LBL, int g) {
  int ll = g & 63, ks2 = (g >> 6) & 1, ec = (g >> 7) & 3, dg = (g >> 9) & 3;
  int d = 32 * dg + (ll & 31);
  int e = 32 * ec + 16 * ks2 + 8 * (ll >> 5);
  float4 z0 = *(const float4*)&Zs[d * 132 + e];
  float4 z1 = *(const float4*)&Zs[d * 132 + e + 4];
  float zv[8] = {z0.x, z0.y, z0.z, z0.w, z1.x, z1.y, z1.z, z1.w};
  ushort hh[8], lo2[8];
  #pragma unroll
  for (int j = 0; j < 8; ++j) {
    hh[j]  = f2bf_trunc(zv[j]);
    lo2[j] = f2bf_rne(zv[j] - bf2f(hh[j]));
  }
  *(ushort4*)&LBH[g * 8]     = make_ushort4(hh[0], hh[1], hh[2], hh[3]);
  *(ushort4*)&LBH[g * 8 + 4] = make_ushort4(hh[4], hh[5], hh[6], hh[7]);
  *(ushort4*)&LBL[g * 8]     = make_ushort4(lo2[0], lo2[1], lo2[2], lo2[3]);
  *(ushort4*)&LBL[g * 8 + 4] = make_ushort4(lo2[4], lo2[5], lo2[6], lo2[7]);
}

// init state + one-time bf16 hi/lo split of X into frag-order XA (row side)
// and XB (transposed side). Block b handles samples 64b..64b+63.
__global__ __launch_bounds__(256) void k_init_split(const float* __restrict__ x,
                                                    const float* __restrict__ means,
                                                    const float* __restrict__ covs,
                                                    float* __restrict__ ws) {
  __shared__ float xt[64 * 132];
  int b = blockIdx.x, t = threadIdx.x;
  int idx = b * 256 + t;
  for (int i = idx; i < KC * DD * DD; i += 256 * 256) ws[OFF_CS + i] = covs[i];
  if (idx < KC * DD) ws[OFF_CUR_M + idx] = means[idx];
  if (idx == 0) {
    ws[OFF_DIFFSQ] = 0.f;
    ((int*)ws)[OFF_DONE] = 0;
    ((int*)ws)[OFF_CTR]  = 0;
  }
  int n0 = b * 64;
  for (int fi = t; fi < 2048; fi += 256) {
    int n = fi >> 5, q = (fi & 31) * 4;
    *(float4*)&xt[n * 132 + q] = *(const float4*)&x[(size_t)(n0 + n) * DD + q];
  }
  __syncthreads();
  ushort* __restrict__ XAH = (ushort*)(ws + OFF_XAH);
  ushort* __restrict__ XAL = (ushort*)(ws + OFF_XAL);
  ushort* __restrict__ XBH = (ushort*)(ws + OFF_XBH);
  ushort* __restrict__ XBL = (ushort*)(ws + OFF_XBL);
  // XA: n = 32*ng+(l&31), e = 32ec+16ks+8(l>>5)+j
  for (int s = t; s < 1024; s += 256) {
    int l = s & 63, ks = (s >> 6) & 1, ec = (s >> 7) & 3, ngl = (s >> 9) & 1;
    int nl = 32 * ngl + (l & 31);
    int e0 = 32 * ec + 16 * ks + 8 * (l >> 5);
    float vv[8];
    *(float4*)&vv[0] = *(const float4*)&xt[nl * 132 + e0];
    *(float4*)&vv[4] = *(const float4*)&xt[nl * 132 + e0 + 4];
    ushort h[8], lo[8];
    #pragma unroll
    for (int j = 0; j < 8; ++j) {
      h[j]  = f2bf_trunc(vv[j]);
      lo[j] = f2bf_rne(vv[j] - bf2f(h[j]));
    }
    size_t base = ((((size_t)((n0 >> 5) + ngl) * 4 + ec) * 2 + ks) * 64 + l) * 8;
    *(ushort4*)&XAH[base]     = make_ushort4(h[0], h[1], h[2], h[3]);
    *(ushort4*)&XAH[base + 4] = make_ushort4(h[4], h[5], h[6], h[7]);
    *(ushort4*)&XAL[base]     = make_ushort4(lo[0], lo[1], lo[2], lo[3]);
    *(ushort4*)&XAL[base + 4] = make_ushort4(lo[4], lo[5], lo[6], lo[7]);
  }
  // XB: e = 32eg+(l&31), n = 16*nb+8(l>>5)+j
  for (int s = t; s < 1024; s += 256) {
    int l = s & 63, nbl = (s >> 6) & 3, eg = (s >> 8) & 3;
    int e = 32 * eg + (l & 31);
    int nl = 16 * nbl + 8 * (l >> 5);
    ushort h[8], lo[8];
    #pragma unroll
    for (int j = 0; j < 8; ++j) {
      float v = xt[(nl + j) * 132 + e];
      h[j]  = f2bf_trunc(v);
      lo[j] = f2bf_rne(v - bf2f(h[j]));
    }
    size_t base = (((size_t)eg * (NS / 16) + (n0 >> 4) + nbl) * 64 + l) * 8;
    *(ushort4*)&XBH[base]     = make_ushort4(h[0], h[1], h[2], h[3]);
    *(ushort4*)&XBH[base + 4] = make_ushort4(h[4], h[5], h[6], h[7]);
    *(ushort4*)&XBL[base]     = make_ushort4(lo[0], lo[1], lo[2], lo[3]);
    *(ushort4*)&XBL[base + 4] = make_ushort4(lo[4], lo[5], lo[6], lo[7]);
  }
}

// Fused update + Cholesky + triangular inverse. One block per component.
// 512 threads = 8 waves (2/SIMD -> 256-VGPR budget; register tiles sized
// to use it). Look-ahead schedule.
__global__ __launch_bounds__(512) void k_fused(float* __restrict__ ws, float* __restrict__ dout,
                                               int guarded, int do_update, int write_out,
                                               int accum_diff, int final_pass) {
  if (guarded && ((const int*)ws)[OFF_DONE]) return;
  __shared__ float m[DD * DD];      // 64 KB, swizzled: C then L
  __shared__ float Zs[DD * 132];    // 66 KB: Linv row-major
  __shared__ float Ws[64 * 68];     // 17 KB: GEMM temp
  __shared__ float invd_s[DD];
  __shared__ float cm_s[DD], nm_s[DD];
  __shared__ float redbuf[2];
  int k = blockIdx.x, t = threadIdx.x;
  int l = t & 63, wv = t >> 6;
  float* __restrict__ CS = ws + OFF_CS + (size_t)k * DD * DD;

  // ---------- phase A: build C in LDS (batched float4 loads, then sweep) ----
  if (do_update) {
    float sw = ws[OFF_SW + k];
    float inv = 1.f / sw;
    float4 s4v[8];
    #pragma unroll
    for (int it = 0; it < 8; ++it)
      s4v[it] = *(const float4*)&CS[(it * 512 + t) * 4];
    if (t < DD) {
      cm_s[t] = ws[OFF_CUR_M + k * DD + t];
      nm_s[t] = ws[OFF_NUM + k * DD + t];
    }
    __syncthreads();
    float* __restrict__ doutC = dout + 1 + KC * DD + (size_t)k * DD * DD;
    #pragma unroll
    for (int it = 0; it < 8; ++it) {
      int idx = (it * 512 + t) * 4;
      float4 s4 = s4v[it];
      int d = idx >> 7, e = idx & 127;
      float md = cm_s[d], nd = nm_s[d];
      float4 me4 = *(const float4*)&cm_s[e];
      float4 ne4 = *(const float4*)&nm_s[e];
      float4 v;
      v.x = (s4.x - md * ne4.x - nd * me4.x + sw * md * me4.x) * inv;
      v.y = (s4.y - md * ne4.y - nd * me4.y + sw * md * me4.y) * inv;
      v.z = (s4.z - md * ne4.z - nd * me4.z + sw * md * me4.z) * inv;
      v.w = (s4.w - md * ne4.w - nd * me4.w + sw * md * me4.w) * inv;
      if (d >= e && d < e + 4) (&v.x)[d - e] += JITTER_;
      *(float4*)&m[swz(d, e)] = v;
      if (write_out) *(float4*)&doutC[idx] = v;
    }
    if (t < DD) {
      float me = cm_s[t], ne = nm_s[t];
      float newm = ne * inv;
      ws[OFF_CUR_M + k * DD + t] = newm;
      if (write_out) dout[1 + k * DD + t] = newm;
      if (accum_diff) {
        float dm = newm - me;
        float s = dm * dm;
        #pragma unroll
        for (int mk2 = 1; mk2 < 64; mk2 <<= 1) s += __shfl_xor(s, mk2, 64);
        if (l == 0) redbuf[wv] = s;
      }
      ws[OFF_NUM + k * DD + t] = 0.f;
    }
    if (t == 0) {
      ws[OFF_SW + k] = 0.f;
      if (final_pass) ws[OFF_LOSSK + k] = 0.f;
    }
  } else {
    #pragma unroll
    for (int it = 0; it < 8; ++it) {
      int idx = (it * 512 + t) * 4;
      float4 c4 = *(const float4*)&CS[idx];
      *(float4*)&m[swz(idx >> 7, idx & 127)] = c4;
    }
    if (t < DD) ws[OFF_NUM + k * DD + t] = 0.f;
    if (t == 0) ws[OFF_SW + k] = 0.f;
  }
  __syncthreads();

  // ---------- phase B: look-ahead Cholesky, PANEL=16, 2-wave FACTOR ----------
  auto FACTOR = [&](int P) {
    int ra = P + l, rb = P + 64 + l;
    bool isA = (wv == 0);
    bool va = ra < DD, vb = rb < DD;
    float A[16], B[16];
    if (va) {
      #pragma unroll
      for (int q = 0; q < 4; ++q) {
        float4 v = *(const float4*)&m[swz(ra, P + 4 * q)];
        A[4*q+0] = v.x; A[4*q+1] = v.y; A[4*q+2] = v.z; A[4*q+3] = v.w;
      }
    }
    if (!isA && vb) {
      #pragma unroll
      for (int q = 0; q < 4; ++q) {
        float4 v = *(const float4*)&m[swz(rb, P + 4 * q)];
        B[4*q+0] = v.x; B[4*q+1] = v.y; B[4*q+2] = v.z; B[4*q+3] = v.w;
      }
    }
    #pragma unroll
    for (int jj = 0; jj < 16; ++jj) {
      float dj = rdlane(A[jj], jj);
      float inv = __builtin_amdgcn_rsqf(dj);
      inv = inv * (1.5f - 0.5f * dj * inv * inv);   // 1 Newton -> ~fp32 exact
      float sj = dj * inv;
      if (va) {
        if (l == jj) A[jj] = sj;
        else if (l > jj) A[jj] *= inv;
      }
      if (!isA && vb) B[jj] *= inv;
      #pragma unroll
      for (int jj2 = jj + 1; jj2 < 16; ++jj2) {
        float c = rdlane(A[jj], jj2);
        if (va && l > jj) A[jj2] -= A[jj] * c;
        if (!isA && vb) B[jj2] -= B[jj] * c;
      }
    }
    if (isA && va) {
      #pragma unroll
      for (int q = 0; q < 4; ++q)
        *(float4*)&m[swz(ra, P + 4 * q)] = make_float4(A[4*q], A[4*q+1], A[4*q+2], A[4*q+3]);
    }
    if (!isA && vb) {
      #pragma unroll
      for (int q = 0; q < 4; ++q)
        *(float4*)&m[swz(rb, P + 4 * q)] = make_float4(B[4*q], B[4*q+1], B[4*q+2], B[4*q+3]);
    }
  };
  // rank-16 8x8 tile update (rest): m[i0..+7][q0..+7] -= panel partial
  auto TILE8 = [&](int i0, int q0, int P) {
    float acc8[8][8] = {};
    #pragma unroll
    for (int pq = 0; pq < 4; ++pq) {
      float4 a[8], b[8];
      #pragma unroll
      for (int r = 0; r < 8; ++r) a[r] = *(const float4*)&m[swz(i0 + r, P + 4 * pq)];
      #pragma unroll
      for (int c = 0; c < 8; ++c) b[c] = *(const float4*)&m[swz(q0 + c, P + 4 * pq)];
      #pragma unroll
      for (int r = 0; r < 8; ++r)
        #pragma unroll
        for (int c = 0; c < 8; ++c)
          acc8[r][c] += a[r].x * b[c].x + a[r].y * b[c].y +
                        a[r].z * b[c].z + a[r].w * b[c].w;
    }
    #pragma unroll
    for (int r = 0; r < 8; ++r)
      #pragma unroll
      for (int cq = 0; cq < 2; ++cq) {
        float4 v = *(const float4*)&m[swz(i0 + r, q0 + 4 * cq)];
        v.x -= acc8[r][4*cq+0]; v.y -= acc8[r][4*cq+1];
        v.z -= acc8[r][4*cq+2]; v.w -= acc8[r][4*cq+3];
        *(float4*)&m[swz(i0 + r, q0 + 4 * cq)] = v;
      }
  };

  if (wv < 2) FACTOR(0);
  __syncthreads();
  for (int P = 0; P < DD - 16; P += 16) {
    int C0 = P + 16;
    // strip: apply panel P to next panel's 16 columns, 2x4 tiles (<=224)
    int nts = ((DD - C0) >> 1) * 4;
    for (int idx = t; idx < nts; idx += 512) {
      int r0 = C0 + 2 * (idx >> 2), q0 = C0 + 4 * (idx & 3);
      float acc2[2][4] = {};
      #pragma unroll
      for (int pq = 0; pq < 4; ++pq) {
        float4 a0 = *(const float4*)&m[swz(r0, P + 4 * pq)];
        float4 a1 = *(const float4*)&m[swz(r0 + 1, P + 4 * pq)];
        float4 b[4];
        #pragma unroll
        for (int c = 0; c < 4; ++c) b[c] = *(const float4*)&m[swz(q0 + c, P + 4 * pq)];
        #pragma unroll
        for (int c = 0; c < 4; ++c) {
          acc2[0][c] += a0.x * b[c].x + a0.y * b[c].y + a0.z * b[c].z + a0.w * b[c].w;
          acc2[1][c] += a1.x * b[c].x + a1.y * b[c].y + a1.z * b[c].z + a1.w * b[c].w;
        }
      }
      float4 v0 = *(const float4*)&m[swz(r0, q0)];
      v0.x -= acc2[0][0]; v0.y -= acc2[0][1]; v0.z -= acc2[0][2]; v0.w -= acc2[0][3];
      *(float4*)&m[swz(r0, q0)] = v0;
      float4 v1 = *(const float4*)&m[swz(r0 + 1, q0)];
      v1.x -= acc2[1][0]; v1.y -= acc2[1][1]; v1.z -= acc2[1][2]; v1.w -= acc2[1][3];
      *(float4*)&m[swz(r0 + 1, q0)] = v1;
    }
    __syncthreads();
    if (wv < 2) {
      FACTOR(C0);                           // overlapped with rest-update
    } else {
      int R0 = P + 32, s = DD - R0;
      if (s > 0) {
        int nt = s >> 3, tri = (nt * (nt + 1)) >> 1;   // 8x8 tiles, <=78
        for (int idx = t - 128; idx < tri; idx += 384) {
          int ti = (int)(0.5f * (sqrtf(8.f * (float)idx + 1.f) - 1.f));
          while (((ti + 1) * (ti + 2)) >> 1 <= idx) ++ti;
          while ((ti * (ti + 1)) >> 1 > idx) --ti;
          int tj = idx - ((ti * (ti + 1)) >> 1);
          TILE8(R0 + 8 * ti, R0 + 8 * tj, P);
        }
      }
    }
    __syncthreads();
  }

  // ---------- phase C: trinv via 32x32 diag blocks + combine GEMMs ----------
  if (t < DD) {
    float dv = m[swz(t, t)];
    invd_s[t] = 1.f / dv;
    if (final_pass) {
      float lg = logf(dv);
      #pragma unroll
      for (int mk2 = 1; mk2 < 64; mk2 <<= 1) lg += __shfl_xor(lg, mk2, 64);
      if (l == 0) redbuf[wv] = lg;
    }
  }
  __syncthreads();
  if (wv < 4) {
    // invert 4 diagonal 32x32 lower-tri blocks; wave wv owns block wv.
    int j = l & 31, r0 = 32 * wv, row = r0 + (l & 31);
    float M[32];
    #pragma unroll
    for (int q = 0; q < 8; ++q) {
      float4 v = *(const float4*)&m[swz(row, r0 + 4 * q)];
      M[4*q+0] = v.x; M[4*q+1] = v.y; M[4*q+2] = v.z; M[4*q+3] = v.w;
    }
    float acc[32];
    #pragma unroll
    for (int i2 = 0; i2 < 32; ++i2) acc[i2] = 0.f;
    #pragma unroll
    for (int p = 0; p < 32; ++p) {
      float zp = (((p == j) ? 1.f : 0.f) - acc[p]) * invd_s[r0 + p];
      Zs[(r0 + p) * 132 + r0 + j] = zp;   // lanes l and l+32: same addr/value
      #pragma unroll
      for (int i2 = p + 1; i2 < 32; ++i2)
        acc[i2] += rdlane(M[p], i2) * zp;
    }
  } else {
    // zero the never-written Zs regions:
    //  a) rows 0..63, cols 64..127   (1024 float4)
    //  b) rows h64..h64+31, cols h64+32..h64+63, h=0,1  (2*256 float4)
    for (int z = t - 256; z < 1536; z += 256) {
      int r, c;
      if (z < 1024) { r = z >> 4; c = 64 + ((z & 15) << 2); }
      else { int z2 = z - 1024; int h = z2 >> 8; int z3 = z2 & 255;
             r = h * 64 + (z3 >> 3); c = h * 64 + 32 + ((z3 & 7) << 2); }
      *(float4*)&Zs[r * 132 + c] = make_float4(0.f, 0.f, 0.f, 0.f);
    }
    if (final_pass && t == 256) ws[OFF_LOGDET + k] = 2.f * (redbuf[0] + redbuf[1]);
  }
  __syncthreads();
  // 32-level combine stage 1: T = L21 * invD(2h)  -> Ws[h*32+i][j]
  {
    int h = t >> 8, i = (t >> 3) & 31, j0 = (t & 7) << 2;
    int rI = h * 64 + 32 + i, cb = h * 64;
    float ax = 0.f, ay = 0.f, az = 0.f, aw = 0.f;
    #pragma unroll
    for (int q0 = 0; q0 < 32; q0 += 4) {
      float4 a  = *(const float4*)&m[swz(rI, cb + q0)];
      float4 z0 = *(const float4*)&Zs[(cb + q0 + 0) * 132 + cb + j0];
      float4 z1 = *(const float4*)&Zs[(cb + q0 + 1) * 132 + cb + j0];
      float4 z2 = *(const float4*)&Zs[(cb + q0 + 2) * 132 + cb + j0];
      float4 z3 = *(const float4*)&Zs[(cb + q0 + 3) * 132 + cb + j0];
      ax += a.x * z0.x + a.y * z1.x + a.z * z2.x + a.w * z3.x;
      ay += a.x * z0.y + a.y * z1.y + a.z * z2.y + a.w * z3.y;
      az += a.x * z0.z + a.y * z1.z + a.z * z2.z + a.w * z3.z;
      aw += a.x * z0.w + a.y * z1.w + a.z * z2.w + a.w * z3.w;
    }
    *(float4*)&Ws[(h * 32 + i) * 68 + j0] = make_float4(ax, ay, az, aw);
  }
  __syncthreads();
  // stage 2: Zs 32-offdiag = -invD(2h+1) * T
  {
    int h = t >> 8, i = (t >> 3) & 31, j0 = (t & 7) << 2;
    int rI = h * 64 + 32 + i;
    float ax = 0.f, ay = 0.f, az = 0.f, aw = 0.f;
    #pragma unroll
    for (int q0 = 0; q0 < 32; q0 += 4) {
      float4 a  = *(const float4*)&Zs[rI * 132 + h * 64 + 32 + q0];
      float4 w0 = *(const float4*)&Ws[(h * 32 + q0 + 0) * 68 + j0];
      float4 w1 = *(const float4*)&Ws[(h * 32 + q0 + 1) * 68 + j0];
      float4 w2 = *(const float4*)&Ws[(h * 32 + q0 + 2) * 68 + j0];
      float4 w3 = *(const float4*)&Ws[(h * 32 + q0 + 3) * 68 + j0];
      ax += a.x * w0.x + a.y * w1.x + a.z * w2.x + a.w * w3.x;
      ay += a.x * w0.y + a.y * w1.y + a.z * w2.y + a.w * w3.y;
      az += a.x * w0.z + a.y * w1.z + a.z * w2.z + a.w * w3.z;
      aw += a.x * w0.w + a.y * w1.w + a.z * w2.w + a.w * w3.w;
    }
    *(float4*)&Zs[rI * 132 + h * 64 + j0] = make_float4(-ax, -ay, -az, -aw);
  }
  __syncthreads();
  // 64-level combine GEMMs on 128 threads (8x4 register tiles) overlapped
  // with bf16 frag stores on threads 128..511.
  ushort* __restrict__ LBH = (ushort*)(ws + OFF_LBH) + (size_t)k * 16384;
  ushort* __restrict__ LBL = (ushort*)(ws + OFF_LBL) + (size_t)k * 16384;
  if (t < 128) {  // GEMM1: W = L21(64) * Ainv -> Ws
    int i0 = (t >> 4) << 3, j0 = (t & 15) << 2;
    float acc4[8][4] = {};
    for (int q0 = 0; q0 < 64; q0 += 4) {
      float4 a[8], b[4];
      #pragma unroll
      for (int r = 0; r < 8; ++r) a[r] = *(const float4*)&m[swz(64 + i0 + r, q0)];
      #pragma unroll
      for (int s2 = 0; s2 < 4; ++s2) b[s2] = *(const float4*)&Zs[(q0 + s2) * 132 + j0];
      #pragma unroll
      for (int r = 0; r < 8; ++r) {
        acc4[r][0] += a[r].x * b[0].x + a[r].y * b[1].x + a[r].z * b[2].x + a[r].w * b[3].x;
        acc4[r][1] += a[r].x * b[0].y + a[r].y * b[1].y + a[r].z * b[2].y + a[r].w * b[3].y;
        acc4[r][2] += a[r].x * b[0].z + a[r].y * b[1].z + a[r].z * b[2].z + a[r].w * b[3].z;
        acc4[r][3] += a[r].x * b[0].w + a[r].y * b[1].w + a[r].z * b[2].w + a[r].w * b[3].w;
      }
    }
    #pragma unroll
    for (int r = 0; r < 8; ++r)
      *(float4*)&Ws[(i0 + r) * 68 + j0] =
          make_float4(acc4[r][0], acc4[r][1], acc4[r][2], acc4[r][3]);
  } else {        // ready frags, part 1: g in [0,768) (all dg<2), 2 each
    #pragma unroll
    for (int it = 0; it < 2; ++it) frag_write(Zs, LBH, LBL, (t - 128) + it * 384);
  }
  __syncthreads();
  if (t < 128) {  // GEMM2: Zs[64+i][j] = -Binv * W
    int i0 = (t >> 4) << 3, j0 = (t & 15) << 2;
    float acc4[8][4] = {};
    for (int q0 = 0; q0 < 64; q0 += 4) {
      float4 a[8], b[4];
      #pragma unroll
      for (int r = 0; r < 8; ++r)
        a[r] = *(const float4*)&Zs[(64 + i0 + r) * 132 + 64 + q0];
      #pragma unroll
      for (int s2 = 0; s2 < 4; ++s2) b[s2] = *(const float4*)&Ws[(q0 + s2) * 68 + j0];
      #pragma unroll
      for (int r = 0; r < 8; ++r) {
        acc4[r][0] += a[r].x * b[0].x + a[r].y * b[1].x + a[r].z * b[2].x + a[r].w * b[3].x;
        acc4[r][1] += a[r].x * b[0].y + a[r].y * b[1].y + a[r].z * b[2].y + a[r].w * b[3].y;
        acc4[r][2] += a[r].x * b[0].z + a[r].y * b[1].z + a[r].z * b[2].z + a[r].w * b[3].z;
        acc4[r][3] += a[r].x * b[0].w + a[r].y * b[1].w + a[r].z * b[2].w + a[r].w * b[3].w;
      }
    }
    #pragma unroll
    for (int r = 0; r < 8; ++r)
      *(float4*)&Zs[(64 + i0 + r) * 132 + j0] =
          make_float4(-acc4[r][0], -acc4[r][1], -acc4[r][2], -acc4[r][3]);
  } else {        // ready frags, part 2: r in [768,1536), 2 each
    #pragma unroll
    for (int it = 0; it < 2; ++it) {
      int r = 768 + (t - 128) + it * 384;
      int g;
      if (r < 1024) g = r;
      else { int rr = r - 1024;
             g = (2 + (rr >> 8)) * 512 + (2 + ((rr >> 7) & 1)) * 128 + (rr & 127); }
      frag_write(Zs, LBH, LBL, g);
    }
  }
  __syncthreads();
  if (t < DD) {   // t = Linv * m  (NEW means)
    const float* __restrict__ mk = ws + OFF_CUR_M + k * DD;
    float s0 = 0.f;
    for (int e = 0; e < DD; e += 4) {
      float4 z = *(const float4*)&Zs[t * 132 + e];
      s0 += z.x * mk[e] + z.y * mk[e + 1] + z.z * mk[e + 2] + z.w * mk[e + 3];
    }
    ws[OFF_T + k * DD + t] = s0;
  } else {        // pending frags: (dg>=2, ec<2), 512 total
    for (int rr = t - 128; rr < 512; rr += 384) {
      int g = (2 + (rr >> 8)) * 512 + ((rr >> 7) & 1) * 128 + (rr & 127);
      frag_write(Zs, LBH, LBL, g);
    }
  }
  // convergence atomics at the very END (off the phase-B critical path);
  // redbuf survives from phase A (phase C writes it only under final_pass,
  // which is mutually exclusive with accum_diff).
  if (accum_diff && t == 0) {
    atomicAdd(&ws[OFF_DIFFSQ], redbuf[0] + redbuf[1]);
    __threadfence();
    int old = atomicAdd((int*)ws + OFF_CTR, 1);
    if ((old & (KC - 1)) == KC - 1) {
      float v = atomicAdd(&ws[OFF_DIFFSQ], 0.f);
      if (v <= EPS2_) atomicExch((int*)ws + OFF_DONE, 1);
      atomicExch(&ws[OFF_DIFFSQ], 0.f);
    }
  }
}

// w[n,k] = ||X Linv^T - t||^2. Block: 128 samples x full 128 d, 4 waves.
// Also zeroes this block's slice of CS for the upcoming k_scatter.
__global__ __launch_bounds__(256) void k_quad(float* __restrict__ ws,
                                              const float* __restrict__ wts,
                                              int guarded, int final_pass) {
  if (guarded && ((const int*)ws)[OFF_DONE]) return;
  __shared__ float warr[128];
  int k = blockIdx.y, bx = blockIdx.x, t = threadIdx.x;
  int l = t & 63, wv = t >> 6;
  int n0 = bx * 128;
  if (t < 128) ws[OFF_CS + (size_t)k * DD * DD + bx * 128 + t] = 0.f;
  const ushort* __restrict__ XAH = (const ushort*)(ws + OFF_XAH);
  const ushort* __restrict__ XAL = (const ushort*)(ws + OFF_XAL);
  const ushort* __restrict__ LBH = (const ushort*)(ws + OFF_LBH) + (size_t)k * 16384;
  const ushort* __restrict__ LBL = (const ushort*)(ws + OFF_LBL) + (size_t)k * 16384;
  f32x16 acc[4] = {};
  size_t ng4 = (size_t)(4 * bx + wv) * 4;
  #pragma unroll
  for (int ec = 0; ec < 4; ++ec) {
    #pragma unroll
    for (int ks = 0; ks < 2; ++ks) {
      size_t aoff = (((ng4 + ec) * 2 + ks) * 64 + l) * 8;
      bf16x8 ah = *(const bf16x8*)&XAH[aoff];
      bf16x8 al = *(const bf16x8*)&XAL[aoff];
      #pragma unroll
      for (int dg = 0; dg < 4; ++dg) {
        size_t boff = ((((size_t)dg * 4 + ec) * 2 + ks) * 64 + l) * 8;
        bf16x8 bh = *(const bf16x8*)&LBH[boff];
        bf16x8 bl = *(const bf16x8*)&LBL[boff];
        acc[dg] = __builtin_amdgcn_mfma_f32_32x32x16_bf16(ah, bh, acc[dg], 0, 0, 0);
        acc[dg] = __builtin_amdgcn_mfma_f32_32x32x16_bf16(ah, bl, acc[dg], 0, 0, 0);
        acc[dg] = __builtin_amdgcn_mfma_f32_32x32x16_bf16(al, bh, acc[dg], 0, 0, 0);
      }
    }
  }
  float tv[4];
  #pragma unroll
  for (int c = 0; c < 4; ++c) tv[c] = ws[OFF_T + k * DD + 32 * c + (l & 31)];
  float part[16];
  #pragma unroll
  for (int r = 0; r < 16; ++r) {
    float s = 0.f;
    #pragma unroll
    for (int c = 0; c < 4; ++c) { float d = acc[c][r] - tv[c]; s += d * d; }
    part[r] = s;
  }
  #pragma unroll
  for (int mk2 = 1; mk2 < 32; mk2 <<= 1)
    #pragma unroll
    for (int r = 0; r < 16; ++r) part[r] += __shfl_xor(part[r], mk2, 64);
  int h = l >> 5;
  if ((l & 31) < 16) {
    int r = l & 31;
    int row = (r & 3) + 8 * (r >> 2) + 4 * h + 32 * wv;   // verified C/D layout
    ws[OFF_W + k * NS + n0 + row] = part[r];
    if (final_pass) warr[row] = part[r];
  }
  if (final_pass) {
    __syncthreads();
    if (t < 64) {
      float s = warr[t] + warr[t + 64];
      #pragma unroll
      for (int mk2 = 1; mk2 < 64; mk2 <<= 1) s += __shfl_xor(s, mk2, 64);
      if (t == 0) atomicAdd(&ws[OFF_LOSSK + k], 0.5f * wts[k] * s);
    }
  }
}

// S_k += (w.X)^T X. 1D grid, XCD-locality decode; 16 chunks x 4 dg x 16 k =
// 1024 blocks, 32KB two-phase LDS reduce. B-frag loads hoisted to the top of
// each iteration (covered by the VALU re-split); __launch_bounds__(256, 2)
// keeps the hoisted frags in registers (r22: 54 -> ~25us).
__global__ __launch_bounds__(256, 2) void k_scatter(float* __restrict__ ws, int guarded) {
  if (guarded && ((const int*)ws)[OFF_DONE]) return;
  __shared__ float Sred[8192];     // 32 KB: [wv(4)][egL(2)][r(16)][l(64)]
  int id = blockIdx.x, t = threadIdx.x;
  int xcd = id & 7, j = id >> 3;
  int chunk = xcd + 8 * (j & 1);   // same-chunk blocks share an XCD's L2
  int dg = (j >> 1) & 3;
  int k = j >> 3;
  int l = t & 63, wv = t >> 6;     // wv = K-quarter within the chunk
  const ushort* __restrict__ XBH = (const ushort*)(ws + OFF_XBH);
  const ushort* __restrict__ XBL = (const ushort*)(ws + OFF_XBL);
  const float* __restrict__ wp = ws + OFF_W + k * NS + chunk * NCHUNK;
  f32x16 acc[4] = {};
  int nb0 = chunk * (NCHUNK / 16) + wv * (NCHUNK / 64);  // 16-sample groups
  int ko = (l >> 5) * 8;
  float zsum = 0.f, wsum = 0.f;
  // prologue: A-frag + w loads for st=0
  size_t aoff = (((size_t)dg * (NS / 16) + nb0) * 64 + l) * 8;
  bf16x8 th = *(const bf16x8*)&XBH[aoff];
  bf16x8 tl = *(const bf16x8*)&XBL[aoff];
  float4 w0 = *(const float4*)&wp[16 * (wv * (NCHUNK / 64)) + ko];
  float4 w1 = *(const float4*)&wp[16 * (wv * (NCHUNK / 64)) + ko + 4];
  for (int st = 0; st < NCHUNK / 64; ++st) {             // 16 iters
    // (1) issue ALL current-st B-frag loads first (8 VMEM in flight)
    bf16x8 bh[4], bl[4];
    #pragma unroll
    for (int eg = 0; eg < 4; ++eg) {
      size_t boff = (((size_t)eg * (NS / 16) + nb0 + st) * 64 + l) * 8;
      bh[eg] = *(const bf16x8*)&XBH[boff];
      bl[eg] = *(const bf16x8*)&XBL[boff];
    }
    // (2) prefetch next-iter A-frags + w (mod-16 clamp, no branch)
    int stn = (st + 1) & (NCHUNK / 64 - 1);
    size_t aoffn = (((size_t)dg * (NS / 16) + nb0 + stn) * 64 + l) * 8;
    bf16x8 thn = *(const bf16x8*)&XBH[aoffn];
    bf16x8 tln = *(const bf16x8*)&XBL[aoffn];
    int wbn = 16 * (wv * (NCHUNK / 64) + stn) + ko;
    float4 w0n = *(const float4*)&wp[wbn];
    float4 w1n = *(const float4*)&wp[wbn + 4];
    // (3) VALU re-split of the A operand — covers the in-flight loads
    float wj[8] = {w0.x, w0.y, w0.z, w0.w, w1.x, w1.y, w1.z, w1.w};
    bf16x8 ah, al;
    #pragma unroll
    for (int jj = 0; jj < 8; ++jj) {
      float xf = bf2f((ushort)th[jj]) + bf2f((ushort)tl[jj]);
      float zf = wj[jj] * xf;
      zsum += zf;                              // num[d] partial
      union { float f; unsigned u; } cz; cz.f = zf;
      ah[jj] = (short)(ushort)(cz.u >> 16);
      union { unsigned u; float f; } ch; ch.u = cz.u & 0xffff0000u;
      al[jj] = (short)f2bf_rne(zf - ch.f);
    }
    if (dg == 0 && (l & 31) == 0) {            // sw partial: 2 lanes/wave
      #pragma unroll
      for (int jj = 0; jj < 8; ++jj) wsum += wj[jj];
    }
    // (4) MFMA block — operands already resident
    #pragma unroll
    for (int eg = 0; eg < 4; ++eg) {
      acc[eg] = __builtin_amdgcn_mfma_f32_32x32x16_bf16(ah, bh[eg], acc[eg], 0, 0, 0);
      acc[eg] = __builtin_amdgcn_mfma_f32_32x32x16_bf16(ah, bl[eg], acc[eg], 0, 0, 0);
      acc[eg] = __builtin_amdgcn_mfma_f32_32x32x16_bf16(al, bh[eg], acc[eg], 0, 0, 0);
    }
    th = thn; tl = tln; w0 = w0n; w1 = w1n;
  }
  // num epilogue: each wave covers a disjoint K-quarter; lanes l and l^32
  // share the same d -> combine then add (d = 32*dg + l).
  zsum += __shfl_xor(zsum, 32, 64);
  if (l < 32) atomicAdd(&ws[OFF_NUM + k * DD + 32 * dg + l], zsum);
  if (dg == 0) {
    wsum += __shfl_xor(wsum, 32, 64);
    if (l == 0) atomicAdd(&ws[OFF_SW + k], wsum);
  }
  // S epilogue: two-phase LDS reduce across the 4 K-quarter waves (32 KB),
  // one atomicAdd per element per block.
  float* __restrict__ S = ws + OFF_CS + (size_t)k * DD * DD;
  #pragma unroll
  for (int p = 0; p < 2; ++p) {
    if (p) __syncthreads();                   // protect Sred reuse
    #pragma unroll
    for (int egL = 0; egL < 2; ++egL)
      #pragma unroll
      for (int r = 0; r < 16; ++r)
        Sred[(wv * 2 + egL) * 1024 + r * 64 + l] = acc[2 * p + egL][r];
    __syncthreads();
    #pragma unroll
    for (int i = 0; i < 8; ++i) {
      int idx = i * 256 + t;
      int ll = idx & 63, r = (idx >> 6) & 15, egL = idx >> 10;
      int base = egL * 1024 + r * 64 + ll;
      float s = Sred[base] + Sred[base + 2048] + Sred[base + 4096] + Sred[base + 6144];
      int h = ll >> 5;
      int drow = 32 * dg + (r & 3) + 8 * (r >> 2) + 4 * h;
      int e = 32 * (2 * p + egL) + (ll & 31);
      atomicAdd(&S[drow * DD + e], s);
    }
  }
}

__global__ void k_lossfin(const float* __restrict__ weights, const float* __restrict__ ws,
                          float* __restrict__ dout) {
  if (threadIdx.x == 0 && blockIdx.x == 0) {
    float base = 0.f;
    for (int k = 0; k < KC; ++k)
      base += weights[k] * 0.5f * (float)NS * ((float)DD * LOG_2PI_ + ws[OFF_LOGDET + k])
            + ws[OFF_LOSSK + k];
    dout[0] = base;
  }
}

extern "C" void kernel_launch(void* const* d_in, const int* in_sizes, int n_in,
                              void* d_out, int out_size, void* d_ws, size_t ws_size,
                              hipStream_t stream) {
  const float* x       = (const float*)d_in[0];
  const float* means   = (const float*)d_in[1];
  const float* covs    = (const float*)d_in[2];
  const float* weights = (const float*)d_in[3];
  float* out = (float*)d_out;
  float* ws  = (float*)d_ws;

  hipLaunchKernelGGL(k_init_split, dim3(NS / 64), dim3(256), 0, stream, x, means, covs, ws);
  // first factorization of the initial covariances (no update phase)
  hipLaunchKernelGGL(k_fused, dim3(16), dim3(512), 0, stream, ws, out, 0, 0, 0, 0, 0);

  // 8 guarded EM iterations: w accumulation, then fused update+chol+trinv
  for (int u = 0; u < 8; ++u) {
    hipLaunchKernelGGL(k_quad,    dim3(128, 16), dim3(256), 0, stream, ws, weights, 1, 0);
    hipLaunchKernelGGL(k_scatter, dim3(1024), dim3(256), 0, stream, ws, 1);
    hipLaunchKernelGGL(k_fused,   dim3(16), dim3(512), 0, stream, ws, out, 1, 1, 0, 1, 0);
  }

  // final (always-executed) update + chol/trinv of c_fin, then loss
  hipLaunchKernelGGL(k_quad,    dim3(128, 16), dim3(256), 0, stream, ws, weights, 0, 0);
  hipLaunchKernelGGL(k_scatter, dim3(1024), dim3(256), 0, stream, ws, 0);
  hipLaunchKernelGGL(k_fused,   dim3(16), dim3(512), 0, stream, ws, out, 0, 1, 1, 0, 1);
  hipLaunchKernelGGL(k_quad,    dim3(128, 16), dim3(256), 0, stream, ws, weights, 0, 1);
  hipLaunchKernelGGL(k_lossfin, dim3(1), dim3(64), 0, stream, weights, ws, out);
}